// Round 10
// baseline (143.174 us; speedup 1.0000x reference)
//
#include <hip/hip_runtime.h>
#include <cmath>

#define NPROP 384
#define NB 2
#define NCLS 11
#define NFG 10
#define BC_TOTAL (NB*NFG)          // 20
#define M_TOTAL (NB*NPROP)         // 768
#define FLAT_PER_IMG (NFG*NPROP)   // 3840
#define DET 100
#define PAIR_SLICE 3072            // per-bc pair capacity

// ws layout (in 4-byte words) — total 222784 words = 891 KB (proven footprint)
#define OFF_BOXES 0                // [BC][N][5]  38400
#define OFF_AREA  38400            // [BC][N]     7680
#define OFF_SCORE 46080            // [BC][N]     7680
#define OFF_SUP   53760            // [BC][N][12] 92160 u32 (rows 48B, 8B-aligned)
#define OFF_KIDX  145920           // [BC][N] u32 kept flat-in-image idx (per-bc slices)
#define OFF_KSC   153600           // [BC][N] kept scores (per-bc slices)
#define OFF_KCNT  161280           // [BC] u32 kept counts (+pad to 32)
#define OFF_PCNT  161312           // [BC] u32 pair counts (+pad to 32)
#define OFF_PAIRS 161344           // [BC][PAIR_SLICE] u32, 61440 total

typedef unsigned long long ull;

__device__ __forceinline__ void mk_corners(float px, float py, float pw, float ph, float pa,
                                           float cxo[4], float cyo[4]) {
    float t = pa * 0.017453292519943295f;
    float ct = cosf(t), st = sinf(t);
    float hx = pw*0.5f, hy = ph*0.5f;
    float lx[4] = {-hx, hx, hx, -hx};
    float ly[4] = {-hy, -hy, hy, hy};
#pragma unroll
    for (int k = 0; k < 4; ++k) {
        cxo[k] = px + lx[k]*ct - ly[k]*st;
        cyo[k] = py + lx[k]*st + ly[k]*ct;
    }
}

// Register-only quirk-faithful intersection area (park-at-centroid + sort-all-24
// + shoelace). Bitonic-32 network keeps everything in VGPRs.
__device__ float inter_area_net(const float ax[4], const float ay[4],
                                const float bx[4], const float by[4]) {
    float d1x[4], d1y[4], d2x[4], d2y[4];
#pragma unroll
    for (int k = 0; k < 4; ++k) {
        int k1 = (k + 1) & 3;
        d1x[k] = ax[k1] - ax[k]; d1y[k] = ay[k1] - ay[k];
        d2x[k] = bx[k1] - bx[k]; d2y[k] = by[k1] - by[k];
    }
    float ex[32], ey[32];
    bool msk[24];
#pragma unroll
    for (int i = 0; i < 4; ++i) {
#pragma unroll
        for (int j = 0; j < 4; ++j) {
            float den = d1x[i]*d2y[j] - d1y[i]*d2x[j];
            float dfx = bx[j]-ax[i], dfy = by[j]-ay[i];
            float dens = (fabsf(den) < 1e-8f) ? 1.0f : den;
            float t = (dfx*d2y[j] - dfy*d2x[j]) / dens;
            float u = (dfx*d1y[i] - dfy*d1x[i]) / dens;
            bool ok = (fabsf(den) >= 1e-8f) && t >= 0.0f && t <= 1.0f
                                            && u >= 0.0f && u <= 1.0f;
            ex[i*4+j] = ax[i] + t*d1x[i];
            ey[i*4+j] = ay[i] + t*d1y[i];
            msk[i*4+j] = ok;
        }
    }
#pragma unroll
    for (int i = 0; i < 4; ++i) {   // corners of A inside B
        bool allp = true, alln = true;
#pragma unroll
        for (int j = 0; j < 4; ++j) {
            float cr = d2x[j]*(ay[i]-by[j]) - d2y[j]*(ax[i]-bx[j]);
            allp = allp && (cr >= -1e-6f);
            alln = alln && (cr <= 1e-6f);
        }
        ex[16+i] = ax[i]; ey[16+i] = ay[i]; msk[16+i] = allp || alln;
    }
#pragma unroll
    for (int i = 0; i < 4; ++i) {   // corners of B inside A
        bool allp = true, alln = true;
#pragma unroll
        for (int j = 0; j < 4; ++j) {
            float cr = d1x[j]*(by[i]-ay[j]) - d1y[j]*(bx[i]-ax[j]);
            allp = allp && (cr >= -1e-6f);
            alln = alln && (cr <= 1e-6f);
        }
        ex[20+i] = bx[i]; ey[20+i] = by[i]; msk[20+i] = allp || alln;
    }
    int nv = 0; float sx = 0.f, sy = 0.f;
#pragma unroll
    for (int k = 0; k < 24; ++k)
        if (msk[k]) { nv++; sx += ex[k]; sy += ey[k]; }
    float fm = (float)(nv > 1 ? nv : 1);
    float cx = sx / fm, cy = sy / fm;
    unsigned key[32];
#pragma unroll
    for (int k = 0; k < 24; ++k) {
        float qx = msk[k] ? ex[k] : cx;
        float qy = msk[k] ? ey[k] : cy;
        ex[k] = qx; ey[k] = qy;
        float dx = qx - cx, dy = qy - cy;        // parked: dx=dy=+0
        float den = fabsf(dx) + fabsf(dy);
        float r = (den > 0.0f) ? dy / den : 0.0f;
        float p = (dx >= 0.0f) ? r : ((dy >= 0.0f) ? 2.0f - r : -2.0f - r);
        p = p + 0.0f;                             // canonicalize -0 -> +0
        unsigned u = __float_as_uint(p);
        u = (u & 0x80000000u) ? ~u : (u | 0x80000000u);
        key[k] = (u & 0xFFFFFFE0u) | (unsigned)k;
    }
#pragma unroll
    for (int k = 24; k < 32; ++k) { key[k] = 0xFFFFFFFFu; ex[k] = 0.f; ey[k] = 0.f; }
#pragma unroll
    for (int k = 2; k <= 32; k <<= 1) {
#pragma unroll
        for (int j = k >> 1; j > 0; j >>= 1) {
#pragma unroll
            for (int i = 0; i < 32; ++i) {
                int l = i ^ j;
                if (l > i) {
                    bool up = ((i & k) == 0);
                    unsigned ka = key[i], kb = key[l];
                    bool sw = up ? (ka > kb) : (ka < kb);
                    float xa = ex[i], xb = ex[l];
                    float ya = ey[i], yb = ey[l];
                    key[i] = sw ? kb : ka; key[l] = sw ? ka : kb;
                    ex[i]  = sw ? xb : xa; ex[l]  = sw ? xa : xb;
                    ey[i]  = sw ? yb : ya; ey[l]  = sw ? ya : yb;
                }
            }
        }
    }
    float s = 0.f;
#pragma unroll
    for (int k = 0; k < 24; ++k) {
        int n = (k + 1 == 24) ? 0 : (k + 1);
        s += ex[k]*ey[n] - ey[k]*ex[n];
    }
    float area = 0.5f * fabsf(s);
    return (nv >= 3) ? area : 0.0f;
}

// evaluate one pair from global box data; set suppress bit (global, device-scope)
__device__ __forceinline__ void eval_pair_glob(float* ws, int bc, int hi, int lo) {
    const float* boxes = ws + OFF_BOXES;
    const float* areaA = ws + OFF_AREA;
    unsigned int* supw = (unsigned int*)(ws + OFF_SUP);
    int rowi = bc*NPROP + hi, rowj = bc*NPROP + lo;
    float axp[4], ayp[4], bxp[4], byp[4];
    mk_corners(boxes[rowi*5+0], boxes[rowi*5+1], boxes[rowi*5+2],
               boxes[rowi*5+3], boxes[rowi*5+4], axp, ayp);
    mk_corners(boxes[rowj*5+0], boxes[rowj*5+1], boxes[rowj*5+2],
               boxes[rowj*5+3], boxes[rowj*5+4], bxp, byp);
    float inter = inter_area_net(axp, ayp, bxp, byp);
    float iou = inter / (areaA[rowi] + areaA[rowj] - inter + 1e-8f);
    if (iou > 0.5f)
        atomicOr(&supw[rowi*12 + (lo >> 5)], 1u << (lo & 31));
}

// Kernel A: one block per (b,cls). decode -> ballot valid-compact ->
// pair enum from LDS (1 LDS atomic/wave) -> global per-bc pair slice.
__global__ __launch_bounds__(384)
void pairgen_kernel(const float* __restrict__ logits,
                    const float* __restrict__ boxreg,
                    const float* __restrict__ rrects,
                    float* __restrict__ ws,
                    float* __restrict__ out) {
    __shared__ float pxL[NPROP], pyL[NPROP], radL[NPROP], areaL[NPROP], scoreL[NPROP];
    __shared__ int   origL[NPROP];
    __shared__ int   wbase[8];
    __shared__ int   pcntS;
    int bc = blockIdx.x, t = threadIdx.x;
    int b = bc / NFG, cls = (bc % NFG) + 1;
    int wv = t >> 6, lane = t & 63;

    int gq = bc*NPROP + t;
    if (gq < NB*DET*6 + NB*DET) out[gq] = 0.0f;   // zero output
    if (t == 0) pcntS = 0;
    // zero this bc's suppress rows (4608 u32)
    {
        unsigned int* supw = (unsigned int*)(ws + OFF_SUP) + bc*NPROP*12;
        for (int k = t; k < NPROP*12; k += NPROP) supw[k] = 0u;
    }
    // decode
    float prob;
    {
        int m = b*NPROP + t;
        float lg[NCLS];
        float mx = -INFINITY;
#pragma unroll
        for (int c = 0; c < NCLS; ++c) { lg[c] = logits[m*NCLS+c]; mx = fmaxf(mx, lg[c]); }
        float sum = 0.f;
#pragma unroll
        for (int c = 0; c < NCLS; ++c) sum += expf(lg[c]-mx);
        prob = expf(lg[cls]-mx) / sum;
        float axc = rrects[m*5+0], ayc = rrects[m*5+1];
        float aw  = rrects[m*5+2], ah  = rrects[m*5+3], aa = rrects[m*5+4];
        const float* rel = boxreg + m*(NCLS*5) + cls*5;
        float dx = rel[0] / 10.0f;
        float dy = rel[1] / 10.0f;
        float dw = fminf(rel[2] / 5.0f, 4.1351665567423205f);
        float dh = fminf(rel[3] / 5.0f, 4.1351665567423205f);
        float da = rel[4];
        float px = dx*aw + axc;
        float py = dy*ah + ayc;
        float pw = expf(dw)*aw;
        float ph = expf(dh)*ah;
        float pa = da*57.29577951308232f + aa;
        float xm = pa + 180.0f;
        float r = fmodf(xm, 360.0f);
        if (r < 0.0f) r += 360.0f;
        pa = r - 180.0f;
        pxL[t]=px; pyL[t]=py; areaL[t]=pw*ph; scoreL[t]=prob;
        radL[t]=0.5f*sqrtf(pw*pw + ph*ph);
        float* boxes = ws + OFF_BOXES;
        int o = bc*NPROP + t;
        boxes[o*5+0]=px; boxes[o*5+1]=py; boxes[o*5+2]=pw; boxes[o*5+3]=ph; boxes[o*5+4]=pa;
        ws[OFF_AREA + o]  = pw*ph;
        ws[OFF_SCORE + o] = prob;
    }
    // ballot-prefix valid compaction (deterministic, no atomics)
    bool vi = prob > 0.05f;
    ull vb = __ballot(vi);
    if (lane == 0) wbase[wv] = __popcll(vb);
    __syncthreads();
    if (t == 0) {
        int s = 0;
#pragma unroll
        for (int w = 0; w < 6; ++w) { int c = wbase[w]; wbase[w] = s; s += c; }
        wbase[6] = s;                            // cnt
    }
    __syncthreads();
    if (vi) origL[wbase[wv] + (int)__popcll(vb & ((1ull << lane) - 1ull))] = t;
    __syncthreads();
    int cnt = wbase[6];

    // pair enumeration: culls + orient; ballot-compact into global slice
    unsigned int* pairs = (unsigned int*)(ws + OFF_PAIRS) + bc*PAIR_SLICE;
    for (int a = wv; a < cnt; a += 6) {
        int ia = origL[a];
        float cxa = pxL[ia], cya = pyL[ia], ra = radL[ia], Aa = areaL[ia], sa = scoreL[ia];
        for (int b0 = a + 1; b0 < cnt; b0 += 64) {
            int bb = b0 + lane;
            bool go = false; int ib = 0;
            if (bb < cnt) {
                ib = origL[bb];
                float ddx = cxa - pxL[ib], ddy = cya - pyL[ib];
                float rr = ra + radL[ib];
                go = (ddx*ddx + ddy*ddy <= rr*rr);
                float Ab = areaL[ib];
                float mn = fminf(Aa, Ab);
                go = go && (3.0f*mn > Aa + Ab);      // else iou <= 0.5 provably
            }
            ull m = __ballot(go);
            int base = 0;
            if (lane == 0 && m) base = atomicAdd(&pcntS, __popcll(m));
            base = __shfl(base, 0);
            if (go) {
                float sb = scoreL[ib];
                bool afirst = (sa > sb) || (sa == sb && ia < ib);
                int hi = afirst ? ia : ib;
                int lo = afirst ? ib : ia;
                int pos = base + (int)__popcll(m & ((1ull << lane) - 1ull));
                if (pos < PAIR_SLICE)
                    pairs[pos] = ((unsigned)hi << 10) | (unsigned)lo;
                else
                    eval_pair_glob(ws, bc, hi, lo);  // overflow fallback
            }
        }
    }
    __syncthreads();
    if (t == 0) ((unsigned int*)(ws + OFF_PCNT))[bc] = (unsigned)pcntS;
}

// Kernel B: 16 blocks per bc; one lane per pair; whole GPU busy
__global__ __launch_bounds__(256)
void heavy_kernel(float* __restrict__ ws) {
    int bc = blockIdx.x >> 4;
    int chunk = blockIdx.x & 15;
    unsigned n = ((const unsigned int*)(ws + OFF_PCNT))[bc];
    if (n > PAIR_SLICE) n = PAIR_SLICE;
    const unsigned int* pairs = (const unsigned int*)(ws + OFF_PAIRS) + bc*PAIR_SLICE;
    for (unsigned p = chunk*256u + threadIdx.x; p < n; p += 4096u) {
        unsigned pk = pairs[p];
        eval_pair_glob(ws, bc, (int)(pk >> 10), (int)(pk & 0x3FFu));
    }
}

// Kernel C: rank-sort + sup staging + register-resident wave walk + kept append
__global__ __launch_bounds__(384)
void nms_kernel(float* __restrict__ ws) {
    __shared__ ull keyL[NPROP];
    __shared__ int orderL[NPROP];
    __shared__ ull supL[NPROP*6];          // 18.4 KB
    __shared__ unsigned char keepS[NPROP];
    __shared__ int wcntS[8];
    int bc = blockIdx.x, t = threadIdx.x;
    int wv = t >> 6, lane = t & 63;
    const float* scoreA = ws + OFF_SCORE;
    const ull* supG = (const ull*)(ws + OFF_SUP);
    float sc = scoreA[bc*NPROP + t];
    bool vi = sc > 0.05f;
    ull myk = vi ? (((ull)__float_as_uint(sc) << 32) | (ull)(0xFFFFFFFFu - (unsigned)t))
                 : (ull)(0xFFFFFFFFu - (unsigned)t);
    keyL[t] = myk;
    keepS[t] = 0;
    ull vb = __ballot(vi);
    if (lane == 0) wcntS[wv] = __popcll(vb);
    __syncthreads();
    {
        int r = 0;
        for (int k = 0; k < NPROP; k += 8) {
            int acc = 0;
#pragma unroll
            for (int q = 0; q < 8; ++q) acc += (keyL[k+q] > myk) ? 1 : 0;
            r += acc;
        }
        orderL[r] = t;
    }
    for (int k = t; k < NPROP*6; k += NPROP) supL[k] = supG[bc*NPROP*6 + k];
    __syncthreads();
    int NV = wcntS[0] + wcntS[1] + wcntS[2] + wcntS[3] + wcntS[4] + wcntS[5];
    if (t < 64) {
        int ord0 = orderL[lane],      ord1 = orderL[64+lane];
        int ord2 = orderL[128+lane],  ord3 = orderL[192+lane];
        int ord4 = orderL[256+lane],  ord5 = orderL[320+lane];
        ull mask = 0ull;                      // lanes 0..5: 384-bit suppressed set
        int o_cur = __shfl(ord0, 0);
        ull row_cur = (lane < 6) ? supL[o_cur*6 + lane] : 0ull;
        for (int p = 0; p < NV; ++p) {
            int pn = (p + 1 < NPROP) ? (p + 1) : 0;
            int seg = pn >> 6, sl = pn & 63;
            int on = __shfl(ord0, sl);
            on = (seg == 1) ? __shfl(ord1, sl) : on;
            on = (seg == 2) ? __shfl(ord2, sl) : on;
            on = (seg == 3) ? __shfl(ord3, sl) : on;
            on = (seg == 4) ? __shfl(ord4, sl) : on;
            on = (seg == 5) ? __shfl(ord5, sl) : on;
            ull row_next = (lane < 6) ? supL[on*6 + lane] : 0ull;  // prefetch
            bool myhit = (lane == (o_cur >> 6)) && ((mask >> (o_cur & 63)) & 1ull);
            ull bal = __ballot(myhit);
            if (bal == 0ull) {                // keep o_cur
                if (lane == 0) keepS[o_cur] = 1;
                mask |= row_cur;
            }
            row_cur = row_next;
            o_cur = on;
        }
    }
    __syncthreads();
    // kept append into this bc's own slice (ballot prefix, no atomics)
    bool kp = keepS[t] != 0;
    ull bal = __ballot(kp);
    if (lane == 0) wcntS[wv] = __popcll(bal);
    __syncthreads();
    if (t == 0) {
        int s = 0;
#pragma unroll
        for (int w = 0; w < 6; ++w) { int c = wcntS[w]; wcntS[w] = s; s += c; }
        ((unsigned int*)(ws + OFF_KCNT))[bc] = (unsigned)s;
    }
    __syncthreads();
    if (kp) {
        int pos = wcntS[wv] + (int)__popcll(bal & ((1ull << lane) - 1ull));
        ((unsigned int*)(ws + OFF_KIDX))[bc*NPROP + pos] = (unsigned)((bc % NFG)*NPROP + t);
        (ws + OFF_KSC)[bc*NPROP + pos] = sc;
    }
}

// Kernel D: 16 blocks per image; concat kept slices as u64 keys; rank count.
__global__ __launch_bounds__(256)
void topk_kernel(const float* __restrict__ ws, float* __restrict__ out) {
    __shared__ ull keyL[FLAT_PER_IMG];
    int b = blockIdx.x >> 4;
    int slice = blockIdx.x & 15;
    int t = threadIdx.x;
    const unsigned int* kidx2 = (const unsigned int*)(ws + OFF_KIDX);
    const float* ksc2 = ws + OFF_KSC;
    const unsigned int* kcnt2 = (const unsigned int*)(ws + OFF_KCNT);
    const float* boxes = ws + OFF_BOXES;
    int offs[NFG], cnts[NFG];
    int K = 0;
#pragma unroll
    for (int fg = 0; fg < NFG; ++fg) {
        cnts[fg] = (int)kcnt2[b*NFG + fg];
        offs[fg] = K;
        K += cnts[fg];
    }
#pragma unroll
    for (int fg = 0; fg < NFG; ++fg) {
        int bc = b*NFG + fg;
        for (int k = t; k < cnts[fg]; k += 256) {
            unsigned sb = __float_as_uint(ksc2[bc*NPROP + k]);
            unsigned f  = kidx2[bc*NPROP + k];
            keyL[offs[fg] + k] = ((ull)sb << 32) | (ull)(0xFFFFFFFFu - f);
        }
    }
    int KP = (K + 15) & ~15;
    for (int k = K + t; k < KP; k += 256) keyL[k] = 0ull;
    __syncthreads();
    int e = slice*256 + t;
    if (e >= K) return;
    ull my = keyL[e];
    int r = 0;
    for (int k = 0; k < KP; k += 16) {
        int acc = 0;
#pragma unroll
        for (int q = 0; q < 16; ++q)
            acc += (keyL[k+q] > my) ? 1 : 0;
        r += acc;
    }
    if (r < DET) {
        unsigned f = 0xFFFFFFFFu - (unsigned)(my & 0xFFFFFFFFu);
        float s = __uint_as_float((unsigned)(my >> 32));
        int src = b*FLAT_PER_IMG + (int)f;
        float* row = out + (b*DET + r)*6;
#pragma unroll
        for (int q = 0; q < 5; ++q) row[q] = boxes[src*5+q];
        row[5] = s;
        out[NB*DET*6 + b*DET + r] = (float)(f / NPROP + 1);
    }
}

extern "C" void kernel_launch(void* const* d_in, const int* in_sizes, int n_in,
                              void* d_out, int out_size, void* d_ws, size_t ws_size,
                              hipStream_t stream) {
    const float* logits = (const float*)d_in[0];
    const float* boxreg = (const float*)d_in[1];
    const float* rrects = (const float*)d_in[2];
    float* out = (float*)d_out;
    float* ws  = (float*)d_ws;
    (void)in_sizes; (void)n_in; (void)out_size; (void)ws_size;

    pairgen_kernel<<<BC_TOTAL, NPROP, 0, stream>>>(logits, boxreg, rrects, ws, out);
    heavy_kernel<<<BC_TOTAL * 16, 256, 0, stream>>>(ws);
    nms_kernel<<<BC_TOTAL, NPROP, 0, stream>>>(ws);
    topk_kernel<<<NB * 16, 256, 0, stream>>>(ws, out);
}